// Round 1
// baseline (769.133 us; speedup 1.0000x reference)
//
#include <hip/hip_runtime.h>

// Problem constants (B=4, S=2048 -> T=8192)
#define T_TOKENS 8192
#define H_DIM 1024
#define F_DIM 4096
#define E_NUM 8

typedef unsigned short u16;
typedef __attribute__((ext_vector_type(8))) short bf16x8;
typedef __attribute__((ext_vector_type(4))) float f32x4;

__device__ __forceinline__ u16 f2bf(float f) {
  union { float f; unsigned int u; } v; v.f = f;
  unsigned int r = v.u + 0x7fffu + ((v.u >> 16) & 1u);
  return (u16)(r >> 16);
}

#define GLOAD_LDS(g, l)                                                        \
  __builtin_amdgcn_global_load_lds(                                            \
      (const __attribute__((address_space(1))) void*)(g),                      \
      (__attribute__((address_space(3))) void*)(l), 16, 0, 0)

// ---------------- fp32 -> bf16 convert (vectorized) ----------------
__global__ void cvt_kernel(const float* __restrict__ in, u16* __restrict__ out,
                           int n4) {
  int i = blockIdx.x * blockDim.x + threadIdx.x;
  int stride = gridDim.x * blockDim.x;
  for (; i < n4; i += stride) {
    float4 v = ((const float4*)in)[i];
    ushort4 o;
    o.x = f2bf(v.x); o.y = f2bf(v.y); o.z = f2bf(v.z); o.w = f2bf(v.w);
    ((ushort4*)out)[i] = o;
  }
}

// ---------------- router: logits + softmax + top2 + renorm ----------------
__global__ void router_kernel(const float* __restrict__ x,
                              const float* __restrict__ gw,
                              float* __restrict__ logits_out,
                              int* __restrict__ sel, float* __restrict__ selw) {
  int wid = threadIdx.x >> 6;
  int lane = threadIdx.x & 63;
  int t = blockIdx.x * 4 + wid;
  const float* xr = x + (size_t)t * H_DIM;
  float acc[E_NUM];
#pragma unroll
  for (int e = 0; e < E_NUM; e++) acc[e] = 0.f;
  for (int h = lane; h < H_DIM; h += 64) {
    float xv = xr[h];
#pragma unroll
    for (int e = 0; e < E_NUM; e++) acc[e] += xv * gw[e * H_DIM + h];
  }
#pragma unroll
  for (int off = 32; off > 0; off >>= 1) {
#pragma unroll
    for (int e = 0; e < E_NUM; e++) acc[e] += __shfl_xor(acc[e], off);
  }
  if (lane < E_NUM) logits_out[(size_t)t * E_NUM + lane] = acc[lane];
  if (lane == 0) {
    float m = acc[0];
#pragma unroll
    for (int e = 1; e < E_NUM; e++) m = fmaxf(m, acc[e]);
    float p[E_NUM];
#pragma unroll
    for (int e = 0; e < E_NUM; e++) p[e] = expf(acc[e] - m);
    int e0 = 0; float p0 = p[0];
#pragma unroll
    for (int e = 1; e < E_NUM; e++) if (p[e] > p0) { p0 = p[e]; e0 = e; }
    int e1 = -1; float p1 = -1.f;
#pragma unroll
    for (int e = 0; e < E_NUM; e++)
      if (e != e0 && p[e] > p1) { p1 = p[e]; e1 = e; }
    float inv = 1.f / (p0 + p1);  // softmax denom cancels in renorm
    sel[t * 2] = e0; sel[t * 2 + 1] = e1;
    selw[t * 2] = p0 * inv; selw[t * 2 + 1] = p1 * inv;
  }
}

// ---------------- scatter: build per-expert pair lists ----------------
__global__ void scatter_kernel(const int* __restrict__ sel,
                               const float* __restrict__ selw,
                               int* __restrict__ cnt, int* __restrict__ list,
                               float* __restrict__ wpair) {
  int t = blockIdx.x * blockDim.x + threadIdx.x;
  if (t >= T_TOKENS) return;
#pragma unroll
  for (int k = 0; k < 2; k++) {
    int e = sel[t * 2 + k];
    int pos = atomicAdd(&cnt[e], 1);
    list[e * T_TOKENS + pos] = t * 2 + k;
    wpair[t * 2 + k] = selw[t * 2 + k];
  }
}

// ---------------- GEMM1: inter = silu(x@w1^T) * (x@w3^T), bf16 out ----------
// 128x128 tile, BK=64, 4 waves of 4x4 16x16x32 fragments, XOR-swizzled LDS.
__global__ __launch_bounds__(256, 2) void gemm1_kernel(
    const u16* __restrict__ xb, const u16* __restrict__ w1b,
    const u16* __restrict__ w3b, const int* __restrict__ cnt,
    const int* __restrict__ list, u16* __restrict__ inter) {
  int e = blockIdx.z;
  int ne = cnt[e];
  int m0 = blockIdx.y * 128;
  if (m0 >= ne) return;
  int nb = blockIdx.x;

  __shared__ u16 al[128 * 64];
  __shared__ u16 b1l[128 * 64];
  __shared__ u16 b3l[128 * 64];
  __shared__ int s_pair[128];

  int tid = threadIdx.x;
  if (tid < 128) {
    int idx = m0 + tid;
    s_pair[tid] = list[e * T_TOKENS + (idx < ne ? idx : 0)];
  }
  __syncthreads();

  // per-thread staging sources (4 rows each); swizzle on global source so the
  // linear global_load_lds dest ends up XOR-swizzled in LDS (rule #21)
  int sc = (((tid & 7) ^ ((tid >> 3) & 7)) << 3);
  const u16 *ab[4], *b1b[4], *b3b[4];
#pragma unroll
  for (int r = 0; r < 4; r++) {
    int row = r * 32 + (tid >> 3);
    ab[r] = xb + (size_t)(s_pair[row] >> 1) * H_DIM + sc;
    b1b[r] = w1b + ((size_t)e * F_DIM + (size_t)nb * 128 + row) * H_DIM + sc;
    b3b[r] = w3b + ((size_t)e * F_DIM + (size_t)nb * 128 + row) * H_DIM + sc;
  }

  int lane = tid & 63;
  int wm = ((tid >> 7) & 1) * 64;
  int wn = ((tid >> 6) & 1) * 64;
  f32x4 zero = {0.f, 0.f, 0.f, 0.f};
  f32x4 acc1[4][4], acc3[4][4];
#pragma unroll
  for (int i = 0; i < 4; i++)
#pragma unroll
    for (int j = 0; j < 4; j++) { acc1[i][j] = zero; acc3[i][j] = zero; }

  for (int kt = 0; kt < H_DIM; kt += 64) {
#pragma unroll
    for (int r = 0; r < 4; r++) {
      int c8 = (r * 256 + tid) * 8;
      GLOAD_LDS(ab[r] + kt, &al[c8]);
      GLOAD_LDS(b1b[r] + kt, &b1l[c8]);
      GLOAD_LDS(b3b[r] + kt, &b3l[c8]);
    }
    __syncthreads();
#pragma unroll
    for (int kk = 0; kk < 2; kk++) {
      int q = kk * 4 + (lane >> 4);
      bf16x8 af[4], bf1[4], bf3[4];
#pragma unroll
      for (int i = 0; i < 4; i++) {
        int row = wm + i * 16 + (lane & 15);
        af[i] = *(const bf16x8*)&al[row * 64 + ((q ^ (row & 7)) << 3)];
      }
#pragma unroll
      for (int j = 0; j < 4; j++) {
        int row = wn + j * 16 + (lane & 15);
        int off = row * 64 + ((q ^ (row & 7)) << 3);
        bf1[j] = *(const bf16x8*)&b1l[off];
        bf3[j] = *(const bf16x8*)&b3l[off];
      }
#pragma unroll
      for (int i = 0; i < 4; i++)
#pragma unroll
        for (int j = 0; j < 4; j++) {
          acc1[i][j] = __builtin_amdgcn_mfma_f32_16x16x32_bf16(
              af[i], bf1[j], acc1[i][j], 0, 0, 0);
          acc3[i][j] = __builtin_amdgcn_mfma_f32_16x16x32_bf16(
              af[i], bf3[j], acc3[i][j], 0, 0, 0);
        }
    }
    __syncthreads();
  }

  // epilogue: SwiGLU, write inter rows (scattered by pair id)
#pragma unroll
  for (int i = 0; i < 4; i++) {
#pragma unroll
    for (int r = 0; r < 4; r++) {
      int ml = wm + i * 16 + (lane >> 4) * 4 + r;
      if (m0 + ml < ne) {
        size_t base =
            (size_t)s_pair[ml] * F_DIM + (size_t)nb * 128 + wn + (lane & 15);
#pragma unroll
        for (int j = 0; j < 4; j++) {
          float h1 = acc1[i][j][r], h3 = acc3[i][j][r];
          float v = h1 / (1.f + __expf(-h1)) * h3;
          inter[base + j * 16] = f2bf(v);
        }
      }
    }
  }
}

// ---------------- GEMM2: out += w * (inter @ w2^T) ----------------
__global__ __launch_bounds__(256, 2) void gemm2_kernel(
    const u16* __restrict__ inter, const u16* __restrict__ w2b,
    const int* __restrict__ cnt, const int* __restrict__ list,
    const float* __restrict__ wpair, float* __restrict__ out) {
  int e = blockIdx.z;
  int ne = cnt[e];
  int m0 = blockIdx.y * 128;
  if (m0 >= ne) return;
  int nb = blockIdx.x;  // over H, 8 blocks

  __shared__ u16 al[128 * 64];
  __shared__ u16 bl[128 * 64];
  __shared__ int s_pair[128];
  __shared__ float s_w[128];

  int tid = threadIdx.x;
  if (tid < 128) {
    int idx = m0 + tid;
    int pr = list[e * T_TOKENS + (idx < ne ? idx : 0)];
    s_pair[tid] = pr;
    s_w[tid] = wpair[pr];
  }
  __syncthreads();

  int sc = (((tid & 7) ^ ((tid >> 3) & 7)) << 3);
  const u16 *ab[4], *bb[4];
#pragma unroll
  for (int r = 0; r < 4; r++) {
    int row = r * 32 + (tid >> 3);
    ab[r] = inter + (size_t)s_pair[row] * F_DIM + sc;
    bb[r] = w2b + ((size_t)e * H_DIM + (size_t)nb * 128 + row) * F_DIM + sc;
  }

  int lane = tid & 63;
  int wm = ((tid >> 7) & 1) * 64;
  int wn = ((tid >> 6) & 1) * 64;
  f32x4 zero = {0.f, 0.f, 0.f, 0.f};
  f32x4 acc[4][4];
#pragma unroll
  for (int i = 0; i < 4; i++)
#pragma unroll
    for (int j = 0; j < 4; j++) acc[i][j] = zero;

  for (int kt = 0; kt < F_DIM; kt += 64) {
#pragma unroll
    for (int r = 0; r < 4; r++) {
      int c8 = (r * 256 + tid) * 8;
      GLOAD_LDS(ab[r] + kt, &al[c8]);
      GLOAD_LDS(bb[r] + kt, &bl[c8]);
    }
    __syncthreads();
#pragma unroll
    for (int kk = 0; kk < 2; kk++) {
      int q = kk * 4 + (lane >> 4);
      bf16x8 af[4], bf[4];
#pragma unroll
      for (int i = 0; i < 4; i++) {
        int row = wm + i * 16 + (lane & 15);
        af[i] = *(const bf16x8*)&al[row * 64 + ((q ^ (row & 7)) << 3)];
      }
#pragma unroll
      for (int j = 0; j < 4; j++) {
        int row = wn + j * 16 + (lane & 15);
        bf[j] = *(const bf16x8*)&bl[row * 64 + ((q ^ (row & 7)) << 3)];
      }
#pragma unroll
      for (int i = 0; i < 4; i++)
#pragma unroll
        for (int j = 0; j < 4; j++)
          acc[i][j] = __builtin_amdgcn_mfma_f32_16x16x32_bf16(
              af[i], bf[j], acc[i][j], 0, 0, 0);
    }
    __syncthreads();
  }

  // epilogue: scale by routing weight, atomicAdd into out (2 adds/elem total,
  // commutative -> deterministic)
#pragma unroll
  for (int i = 0; i < 4; i++) {
#pragma unroll
    for (int r = 0; r < 4; r++) {
      int ml = wm + i * 16 + (lane >> 4) * 4 + r;
      if (m0 + ml < ne) {
        int pr = s_pair[ml];
        float w = s_w[ml];
        float* ob =
            out + (size_t)(pr >> 1) * H_DIM + (size_t)nb * 128 + wn + (lane & 15);
#pragma unroll
        for (int j = 0; j < 4; j++) atomicAdd(ob + j * 16, acc[i][j][r] * w);
      }
    }
  }
}

// ---------------- workspace layout (bytes) ----------------
#define XB_OFF 0UL
#define W1B_OFF (XB_OFF + (size_t)T_TOKENS * H_DIM * 2)          // 16 MiB
#define W3B_OFF (W1B_OFF + (size_t)E_NUM * F_DIM * H_DIM * 2)    // +64 MiB
#define W2B_OFF (W3B_OFF + (size_t)E_NUM * F_DIM * H_DIM * 2)
#define INTER_OFF (W2B_OFF + (size_t)E_NUM * F_DIM * H_DIM * 2)
#define CNT_OFF (INTER_OFF + (size_t)2 * T_TOKENS * F_DIM * 2)   // +128 MiB
#define LIST_OFF (CNT_OFF + 256)
#define WPAIR_OFF (LIST_OFF + (size_t)E_NUM * T_TOKENS * 4)
#define SEL_OFF (WPAIR_OFF + (size_t)2 * T_TOKENS * 4)
#define SELW_OFF (SEL_OFF + (size_t)2 * T_TOKENS * 4)

extern "C" void kernel_launch(void* const* d_in, const int* in_sizes, int n_in,
                              void* d_out, int out_size, void* d_ws,
                              size_t ws_size, hipStream_t stream) {
  const float* x = (const float*)d_in[0];
  const float* gw = (const float*)d_in[1];
  const float* w1 = (const float*)d_in[2];
  const float* w2 = (const float*)d_in[3];
  const float* w3 = (const float*)d_in[4];
  float* out = (float*)d_out;
  float* logits_out = out + (size_t)T_TOKENS * H_DIM;

  char* ws = (char*)d_ws;
  u16* xb = (u16*)(ws + XB_OFF);
  u16* w1b = (u16*)(ws + W1B_OFF);
  u16* w3b = (u16*)(ws + W3B_OFF);
  u16* w2b = (u16*)(ws + W2B_OFF);
  u16* inter = (u16*)(ws + INTER_OFF);
  int* cnt = (int*)(ws + CNT_OFF);
  int* list = (int*)(ws + LIST_OFF);
  float* wpair = (float*)(ws + WPAIR_OFF);
  int* sel = (int*)(ws + SEL_OFF);
  float* selw = (float*)(ws + SELW_OFF);

  hipMemsetAsync(d_out, 0, (size_t)T_TOKENS * H_DIM * sizeof(float), stream);
  hipMemsetAsync(cnt, 0, 256, stream);

  cvt_kernel<<<2048, 256, 0, stream>>>(x, xb, T_TOKENS * H_DIM / 4);
  cvt_kernel<<<2048, 256, 0, stream>>>(w1, w1b, E_NUM * F_DIM * H_DIM / 4);
  cvt_kernel<<<2048, 256, 0, stream>>>(w3, w3b, E_NUM * F_DIM * H_DIM / 4);
  cvt_kernel<<<2048, 256, 0, stream>>>(w2, w2b, E_NUM * F_DIM * H_DIM / 4);

  router_kernel<<<T_TOKENS / 4, 256, 0, stream>>>(x, gw, logits_out, sel, selw);
  scatter_kernel<<<T_TOKENS / 256, 256, 0, stream>>>(sel, selw, cnt, list,
                                                     wpair);

  gemm1_kernel<<<dim3(F_DIM / 128, T_TOKENS / 128, E_NUM), 256, 0, stream>>>(
      xb, w1b, w3b, cnt, list, inter);
  gemm2_kernel<<<dim3(H_DIM / 128, T_TOKENS / 128, E_NUM), 256, 0, stream>>>(
      inter, w2b, cnt, list, wpair, out);
}